// Round 1
// baseline (5217.419 us; speedup 1.0000x reference)
//
#include <hip/hip_runtime.h>
#include <hip/hip_bf16.h>

#define EPS 1e-5f
#define SCALE 0.17677669529663687f   // 32^-0.5

// ---------------------------------------------------------------------------
// Tiled fp32 GEMM + BN epilogue.
// OUT[b][o][n] = BN( sum_c W[o][c] * X[b][c][n] )
// X: (B, C, N), W: (O, C), OUT: (B, O, N).  C%16==0, O%64==0, N%64==0.
// ---------------------------------------------------------------------------
#define TILE 64
#define KSTEP 16

__global__ __launch_bounds__(256) void gemm_bn_kernel(
    const float* __restrict__ X, const float* __restrict__ W,
    const float* __restrict__ gamma, const float* __restrict__ beta,
    const float* __restrict__ mean, const float* __restrict__ var,
    float* __restrict__ OUT, int C, int O, int N) {
  __shared__ float Ws[KSTEP][TILE + 4];  // [kk][o_local], +4 pad keeps 16B align
  __shared__ float Xs[KSTEP][TILE + 4];  // [kk][n_local]

  const int tx = threadIdx.x, ty = threadIdx.y;
  const int t = ty * 16 + tx;
  const int b = blockIdx.z;
  const int o0 = blockIdx.y * TILE;
  const int n0 = blockIdx.x * TILE;
  const float* Xb = X + (size_t)b * C * N;

  // staging maps
  const int wo = t >> 2;          // 0..63  (o_local)
  const int wc = (t & 3) * 4;     // 0,4,8,12 (c_local)
  const int xr = t >> 4;          // 0..15  (c_local)
  const int xc = (t & 15) * 4;    // 0..60  (n_local)

  float acc[4][4] = {};

  for (int c0 = 0; c0 < C; c0 += KSTEP) {
    float4 wv = *(const float4*)&W[(size_t)(o0 + wo) * C + c0 + wc];
    Ws[wc + 0][wo] = wv.x;
    Ws[wc + 1][wo] = wv.y;
    Ws[wc + 2][wo] = wv.z;
    Ws[wc + 3][wo] = wv.w;
    *(float4*)&Xs[xr][xc] = *(const float4*)&Xb[(size_t)(c0 + xr) * N + n0 + xc];
    __syncthreads();
#pragma unroll
    for (int kk = 0; kk < KSTEP; ++kk) {
      float4 a = *(const float4*)&Ws[kk][ty * 4];
      float4 bv = *(const float4*)&Xs[kk][tx * 4];
      acc[0][0] += a.x * bv.x; acc[0][1] += a.x * bv.y; acc[0][2] += a.x * bv.z; acc[0][3] += a.x * bv.w;
      acc[1][0] += a.y * bv.x; acc[1][1] += a.y * bv.y; acc[1][2] += a.y * bv.z; acc[1][3] += a.y * bv.w;
      acc[2][0] += a.z * bv.x; acc[2][1] += a.z * bv.y; acc[2][2] += a.z * bv.z; acc[2][3] += a.z * bv.w;
      acc[3][0] += a.w * bv.x; acc[3][1] += a.w * bv.y; acc[3][2] += a.w * bv.z; acc[3][3] += a.w * bv.w;
    }
    __syncthreads();
  }

#pragma unroll
  for (int i = 0; i < 4; ++i) {
    int o = o0 + ty * 4 + i;
    float inv = gamma[o] * rsqrtf(var[o] + EPS);
    float add = beta[o] - mean[o] * inv;
    float4 r;
    r.x = acc[i][0] * inv + add;
    r.y = acc[i][1] * inv + add;
    r.z = acc[i][2] * inv + add;
    r.w = acc[i][3] * inv + add;
    *(float4*)&OUT[((size_t)b * O + o) * N + n0 + tx * 4] = r;
  }
}

// ---------------------------------------------------------------------------
// Streaming softmax attention. qkv: (B, 1024, 1600); per head h the 128 rows
// [h*128, h*128+128) are q(32), k(32), v(64). One wave handles 64 queries of
// one (b,h); streams key/value tiles of 64 through LDS; exp without max
// subtraction (logits ~N(0,1), fp32 exp safe). Writes y (B,512,1600).
// ---------------------------------------------------------------------------
__global__ __launch_bounds__(64) void attn_kernel(
    const float* __restrict__ qkv, float* __restrict__ y) {
  const int N = 1600;
  const int bh = blockIdx.y;  // 0..63
  const int b = bh >> 3, h = bh & 7;
  const int n = blockIdx.x * 64 + threadIdx.x;  // query index
  const float* base = qkv + (size_t)(b * 1024 + h * 128) * N;

  float q[32];
#pragma unroll
  for (int kk = 0; kk < 32; ++kk) q[kk] = base[(size_t)kk * N + n] * SCALE;

  __shared__ float ks[32][64];
  __shared__ float vs[64][64];

  float num[64];
#pragma unroll
  for (int d = 0; d < 64; ++d) num[d] = 0.f;
  float den = 0.f;

  for (int m0 = 0; m0 < N; m0 += 64) {
#pragma unroll
    for (int kk = 0; kk < 32; ++kk)
      ks[kk][threadIdx.x] = base[(size_t)(32 + kk) * N + m0 + threadIdx.x];
#pragma unroll
    for (int d = 0; d < 64; ++d)
      vs[d][threadIdx.x] = base[(size_t)(64 + d) * N + m0 + threadIdx.x];
    __syncthreads();

    for (int mm = 0; mm < 64; ++mm) {
      float s = 0.f;
#pragma unroll
      for (int kk = 0; kk < 32; ++kk) s += q[kk] * ks[kk][mm];
      float p = __expf(s);
      den += p;
#pragma unroll
      for (int d = 0; d < 64; ++d) num[d] += p * vs[d][mm];
    }
    __syncthreads();
  }

  float rden = 1.f / den;
  float* yb = y + (size_t)(b * 512 + h * 64) * N + n;
#pragma unroll
  for (int d = 0; d < 64; ++d) yb[(size_t)d * N] = num[d] * rden;
}

// ---------------------------------------------------------------------------
// Depthwise 3x3 conv (SAME, zero pad) on v + BN, accumulated into y.
// v[b][c][n] lives in qkv at row (c/64)*128 + 64 + (c%64).
// ---------------------------------------------------------------------------
__global__ __launch_bounds__(256) void pe_add_kernel(
    const float* __restrict__ qkv, const float* __restrict__ pw,
    const float* __restrict__ gamma, const float* __restrict__ beta,
    const float* __restrict__ mean, const float* __restrict__ var,
    float* __restrict__ y) {
  const int idx = blockIdx.x * 256 + threadIdx.x;  // over 8*512*1600
  const int n = idx % 1600;
  const int bc = idx / 1600;
  const int c = bc % 512;
  const int b = bc / 512;
  const int hh = n / 40, ww = n % 40;
  const int head = c >> 6, d = c & 63;
  const float* v = qkv + (size_t)(b * 1024 + head * 128 + 64 + d) * 1600;
  const float* wk = pw + c * 9;

  float s = 0.f;
#pragma unroll
  for (int dy = -1; dy <= 1; ++dy) {
#pragma unroll
    for (int dx = -1; dx <= 1; ++dx) {
      int yy = hh + dy, xx = ww + dx;
      if (yy >= 0 && yy < 40 && xx >= 0 && xx < 40)
        s += wk[(dy + 1) * 3 + (dx + 1)] * v[yy * 40 + xx];
    }
  }
  float inv = gamma[c] * rsqrtf(var[c] + EPS);
  y[idx] += s * inv + (beta[c] - mean[c] * inv);
}

// ---------------------------------------------------------------------------
extern "C" void kernel_launch(void* const* d_in, const int* in_sizes, int n_in,
                              void* d_out, int out_size, void* d_ws, size_t ws_size,
                              hipStream_t stream) {
  const float* x          = (const float*)d_in[0];
  const float* qkv_w      = (const float*)d_in[1];
  const float* qkv_gamma  = (const float*)d_in[2];
  const float* qkv_beta   = (const float*)d_in[3];
  const float* qkv_mean   = (const float*)d_in[4];
  const float* qkv_var    = (const float*)d_in[5];
  const float* pe_w       = (const float*)d_in[6];
  const float* pe_gamma   = (const float*)d_in[7];
  const float* pe_beta    = (const float*)d_in[8];
  const float* pe_mean    = (const float*)d_in[9];
  const float* pe_var     = (const float*)d_in[10];
  const float* proj_w     = (const float*)d_in[11];
  const float* proj_gamma = (const float*)d_in[12];
  const float* proj_beta  = (const float*)d_in[13];
  const float* proj_mean  = (const float*)d_in[14];
  const float* proj_var   = (const float*)d_in[15];
  float* out = (float*)d_out;

  // workspace: qkv (8*1024*1600 f32 = 52.4 MB) then y (8*512*1600 f32 = 26.2 MB)
  float* ws_qkv = (float*)d_ws;
  float* ws_y   = ws_qkv + (size_t)8 * 1024 * 1600;

  // 1) QKV = BN(conv1x1(x, qkv_w))
  {
    dim3 grid(1600 / TILE, 1024 / TILE, 8), block(16, 16);
    gemm_bn_kernel<<<grid, block, 0, stream>>>(
        x, qkv_w, qkv_gamma, qkv_beta, qkv_mean, qkv_var, ws_qkv, 512, 1024, 1600);
  }
  // 2) softmax attention -> y
  {
    dim3 grid(1600 / 64, 64), block(64);
    attn_kernel<<<grid, block, 0, stream>>>(ws_qkv, ws_y);
  }
  // 3) y += BN(dwconv3x3(v, pe_w))
  {
    dim3 grid(8 * 512 * 1600 / 256), block(256);
    pe_add_kernel<<<grid, block, 0, stream>>>(
        ws_qkv, pe_w, pe_gamma, pe_beta, pe_mean, pe_var, ws_y);
  }
  // 4) out = BN(conv1x1(y, proj_w))
  {
    dim3 grid(1600 / TILE, 512 / TILE, 8), block(16, 16);
    gemm_bn_kernel<<<grid, block, 0, stream>>>(
        ws_y, proj_w, proj_gamma, proj_beta, proj_mean, proj_var, out, 512, 512, 1600);
  }
}

// Round 2
// 580.026 us; speedup vs baseline: 8.9951x; 8.9951x over previous
//
#include <hip/hip_runtime.h>
#include <hip/hip_bf16.h>

#define EPS 1e-5f
#define SCALE 0.17677669529663687f   // 32^-0.5

typedef __attribute__((ext_vector_type(8))) short bf16x8;
typedef __attribute__((ext_vector_type(4))) float f32x4;

__device__ __forceinline__ unsigned short f2bf(float x) {
  union { float f; unsigned int u; } a; a.f = x;
  unsigned int r = a.u + 0x7FFFu + ((a.u >> 16) & 1u);
  return (unsigned short)(r >> 16);
}

// ---------------------------------------------------------------------------
// Generic tiled fp32 GEMM + BN epilogue (used for proj).
// OUT[b][o][n] = BN( sum_c W[o][c] * X[b][c][n] )
// ---------------------------------------------------------------------------
#define TILE 64
#define KSTEP 16

__global__ __launch_bounds__(256) void gemm_bn_kernel(
    const float* __restrict__ X, const float* __restrict__ W,
    const float* __restrict__ gamma, const float* __restrict__ beta,
    const float* __restrict__ mean, const float* __restrict__ var,
    float* __restrict__ OUT, int C, int O, int N) {
  __shared__ float Ws[KSTEP][TILE + 4];
  __shared__ float Xs[KSTEP][TILE + 4];

  const int tx = threadIdx.x, ty = threadIdx.y;
  const int t = ty * 16 + tx;
  const int b = blockIdx.z;
  const int o0 = blockIdx.y * TILE;
  const int n0 = blockIdx.x * TILE;
  const float* Xb = X + (size_t)b * C * N;

  const int wo = t >> 2;
  const int wc = (t & 3) * 4;
  const int xr = t >> 4;
  const int xc = (t & 15) * 4;

  float acc[4][4] = {};

  for (int c0 = 0; c0 < C; c0 += KSTEP) {
    float4 wv = *(const float4*)&W[(size_t)(o0 + wo) * C + c0 + wc];
    Ws[wc + 0][wo] = wv.x;
    Ws[wc + 1][wo] = wv.y;
    Ws[wc + 2][wo] = wv.z;
    Ws[wc + 3][wo] = wv.w;
    *(float4*)&Xs[xr][xc] = *(const float4*)&Xb[(size_t)(c0 + xr) * N + n0 + xc];
    __syncthreads();
#pragma unroll
    for (int kk = 0; kk < KSTEP; ++kk) {
      float4 a = *(const float4*)&Ws[kk][ty * 4];
      float4 bv = *(const float4*)&Xs[kk][tx * 4];
      acc[0][0] += a.x * bv.x; acc[0][1] += a.x * bv.y; acc[0][2] += a.x * bv.z; acc[0][3] += a.x * bv.w;
      acc[1][0] += a.y * bv.x; acc[1][1] += a.y * bv.y; acc[1][2] += a.y * bv.z; acc[1][3] += a.y * bv.w;
      acc[2][0] += a.z * bv.x; acc[2][1] += a.z * bv.y; acc[2][2] += a.z * bv.z; acc[2][3] += a.z * bv.w;
      acc[3][0] += a.w * bv.x; acc[3][1] += a.w * bv.y; acc[3][2] += a.w * bv.z; acc[3][3] += a.w * bv.w;
    }
    __syncthreads();
  }

#pragma unroll
  for (int i = 0; i < 4; ++i) {
    int o = o0 + ty * 4 + i;
    float inv = gamma[o] * rsqrtf(var[o] + EPS);
    float add = beta[o] - mean[o] * inv;
    float4 r;
    r.x = acc[i][0] * inv + add;
    r.y = acc[i][1] * inv + add;
    r.z = acc[i][2] * inv + add;
    r.w = acc[i][3] * inv + add;
    *(float4*)&OUT[((size_t)b * O + o) * N + n0 + tx * 4] = r;
  }
}

// ---------------------------------------------------------------------------
// QKV GEMM + BN with split epilogue:
//   rows r%128 in [0,32):  q  -> qT (B,8,N,32) bf16, pre-scaled by SCALE
//   rows r%128 in [32,64): k  -> kT (B,8,N,32) bf16
//   rows r%128 in [64,128): v -> vf (B,512,N) fp32  AND  vb (B,512,N) bf16
// C=512, O=1024, N=1600 hardcoded.
// ---------------------------------------------------------------------------
__global__ __launch_bounds__(256) void qkv_gemm_kernel(
    const float* __restrict__ X, const float* __restrict__ W,
    const float* __restrict__ gamma, const float* __restrict__ beta,
    const float* __restrict__ mean, const float* __restrict__ var,
    short* __restrict__ qT, short* __restrict__ kT,
    float* __restrict__ vf, short* __restrict__ vb) {
  const int C = 512, N = 1600;
  __shared__ float Ws[KSTEP][TILE + 4];
  __shared__ float Xs[KSTEP][TILE + 4];

  const int tx = threadIdx.x, ty = threadIdx.y;
  const int t = ty * 16 + tx;
  const int b = blockIdx.z;
  const int o0 = blockIdx.y * TILE;
  const int n0 = blockIdx.x * TILE;
  const float* Xb = X + (size_t)b * C * N;

  const int wo = t >> 2;
  const int wc = (t & 3) * 4;
  const int xr = t >> 4;
  const int xc = (t & 15) * 4;

  float acc[4][4] = {};

  for (int c0 = 0; c0 < C; c0 += KSTEP) {
    float4 wv = *(const float4*)&W[(size_t)(o0 + wo) * C + c0 + wc];
    Ws[wc + 0][wo] = wv.x;
    Ws[wc + 1][wo] = wv.y;
    Ws[wc + 2][wo] = wv.z;
    Ws[wc + 3][wo] = wv.w;
    *(float4*)&Xs[xr][xc] = *(const float4*)&Xb[(size_t)(c0 + xr) * N + n0 + xc];
    __syncthreads();
#pragma unroll
    for (int kk = 0; kk < KSTEP; ++kk) {
      float4 a = *(const float4*)&Ws[kk][ty * 4];
      float4 bv = *(const float4*)&Xs[kk][tx * 4];
      acc[0][0] += a.x * bv.x; acc[0][1] += a.x * bv.y; acc[0][2] += a.x * bv.z; acc[0][3] += a.x * bv.w;
      acc[1][0] += a.y * bv.x; acc[1][1] += a.y * bv.y; acc[1][2] += a.y * bv.z; acc[1][3] += a.y * bv.w;
      acc[2][0] += a.z * bv.x; acc[2][1] += a.z * bv.y; acc[2][2] += a.z * bv.z; acc[2][3] += a.z * bv.w;
      acc[3][0] += a.w * bv.x; acc[3][1] += a.w * bv.y; acc[3][2] += a.w * bv.z; acc[3][3] += a.w * bv.w;
    }
    __syncthreads();
  }

#pragma unroll
  for (int i = 0; i < 4; ++i) {
    int o = o0 + ty * 4 + i;
    float inv = gamma[o] * rsqrtf(var[o] + EPS);
    float add = beta[o] - mean[o] * inv;
    float v0 = acc[i][0] * inv + add;
    float v1 = acc[i][1] * inv + add;
    float v2 = acc[i][2] * inv + add;
    float v3 = acc[i][3] * inv + add;
    int h = o >> 7, r = o & 127;
    int n = n0 + tx * 4;
    if (r < 64) {                      // wave-uniform (16-row span in 32-block)
      bool isq = (r < 32);
      short* dst = isq ? qT : kT;
      int kk = isq ? r : r - 32;
      float sc = isq ? SCALE : 1.f;
      size_t base = ((size_t)(b * 8 + h) * N + n) * 32 + kk;
      dst[base +  0] = (short)f2bf(v0 * sc);
      dst[base + 32] = (short)f2bf(v1 * sc);
      dst[base + 64] = (short)f2bf(v2 * sc);
      dst[base + 96] = (short)f2bf(v3 * sc);
    } else {
      int ch = h * 64 + (r - 64);
      size_t base = ((size_t)b * 512 + ch) * N + n;
      *(float4*)&vf[base] = make_float4(v0, v1, v2, v3);
      ushort4 u;
      u.x = f2bf(v0); u.y = f2bf(v1); u.z = f2bf(v2); u.w = f2bf(v3);
      *(ushort4*)&vb[base] = u;
    }
  }
}

// ---------------------------------------------------------------------------
// MFMA flash-style attention. Block = 4 waves, one 64-query n-tile per block.
// Waves split the 25 m-tiles of 64 keys; partial (num,den) merged via LDS.
// qT/kT: (B,8,N,32) bf16 (q pre-scaled). vb: (B,512,N) bf16. y: (B,512,N) f32.
// ---------------------------------------------------------------------------
__global__ __launch_bounds__(256) void attn_mfma_kernel(
    const short* __restrict__ qT, const short* __restrict__ kT,
    const short* __restrict__ vb, float* __restrict__ y) {
  const int N = 1600;
  const int PS = 72;  // P-tile LDS row stride (bf16): 16B-aligned b128 reads
  __shared__ __align__(16) unsigned short Plds[4][64 * PS];
  __shared__ float den_lds[4][64];
  __shared__ float rden[64];

  const int t = threadIdx.x;
  const int w = t >> 6, lane = t & 63, quad = lane >> 4, l16 = lane & 15;
  const int bh = blockIdx.y, b = bh >> 3, h = bh & 7;
  const int n0 = blockIdx.x * 64;

  const short* qTb = qT + (size_t)(b * 8 + h) * N * 32;
  const short* kTb = kT + (size_t)(b * 8 + h) * N * 32;
  const short* vbb = vb + ((size_t)b * 512 + h * 64) * N;

  // q fragments (A-operand, M=n K=kk=32), resident across the whole m-loop
  bf16x8 qf[4];
#pragma unroll
  for (int i = 0; i < 4; ++i)
    qf[i] = *(const bf16x8*)(qTb + (size_t)(n0 + i * 16 + l16) * 32 + quad * 8);

  f32x4 acc[4][4];
#pragma unroll
  for (int i = 0; i < 4; ++i)
#pragma unroll
    for (int j = 0; j < 4; ++j) { acc[i][j][0] = 0.f; acc[i][j][1] = 0.f; acc[i][j][2] = 0.f; acc[i][j][3] = 0.f; }
  float den[4][4] = {};

  unsigned short* Pw = &Plds[w][0];
  const f32x4 zero4 = {0.f, 0.f, 0.f, 0.f};

  for (int mt = w; mt < 25; mt += 4) {
    const int m0 = mt * 64;
    // K fragments (B-operand, K=kk, N=m)
    bf16x8 kf[4];
#pragma unroll
    for (int j = 0; j < 4; ++j)
      kf[j] = *(const bf16x8*)(kTb + (size_t)(m0 + j * 16 + l16) * 32 + quad * 8);

    // S = (q*SCALE)^T K, then P = exp(S) -> LDS (n-major, for A-layout reads)
#pragma unroll
    for (int i = 0; i < 4; ++i) {
#pragma unroll
      for (int j = 0; j < 4; ++j) {
        f32x4 s = __builtin_amdgcn_mfma_f32_16x16x32_bf16(qf[i], kf[j], zero4, 0, 0, 0);
#pragma unroll
        for (int r = 0; r < 4; ++r) {
          float p = __expf(s[r]);
          den[i][r] += p;
          Pw[(i * 16 + quad * 4 + r) * PS + j * 16 + l16] = f2bf(p);
        }
      }
    }

    // P A-fragments back from LDS (transpose round-trip)
    bf16x8 pf[4][2];
#pragma unroll
    for (int i = 0; i < 4; ++i)
#pragma unroll
      for (int c = 0; c < 2; ++c)
        pf[i][c] = *(const bf16x8*)(Pw + (i * 16 + l16) * PS + c * 32 + quad * 8);

    // out += P * V^T   (A = P: n x m, B = v^T: m x d)
#pragma unroll
    for (int c = 0; c < 2; ++c) {
#pragma unroll
      for (int j = 0; j < 4; ++j) {
        bf16x8 vfr = *(const bf16x8*)(vbb + (size_t)(j * 16 + l16) * N + m0 + c * 32 + quad * 8);
#pragma unroll
        for (int i = 0; i < 4; ++i)
          acc[i][j] = __builtin_amdgcn_mfma_f32_16x16x32_bf16(pf[i][c], vfr, acc[i][j], 0, 0, 0);
      }
    }
  }

  // reduce den across the 16 lanes holding the same row
#pragma unroll
  for (int mask = 1; mask <= 8; mask <<= 1)
#pragma unroll
    for (int i = 0; i < 4; ++i)
#pragma unroll
      for (int r = 0; r < 4; ++r)
        den[i][r] += __shfl_xor(den[i][r], mask, 64);
  if (l16 == 0) {
#pragma unroll
    for (int i = 0; i < 4; ++i)
#pragma unroll
      for (int r = 0; r < 4; ++r)
        den_lds[w][i * 16 + quad * 4 + r] = den[i][r];
  }
  __syncthreads();
  if (t < 64)
    rden[t] = 1.f / (den_lds[0][t] + den_lds[1][t] + den_lds[2][t] + den_lds[3][t]);

  // cross-wave merge + normalized, n-contiguous store (R aliases Plds)
  float* R = (float*)&Plds[0][0];  // [w][16 rows][68 cols]
#pragma unroll 1
  for (int i = 0; i < 4; ++i) {
    __syncthreads();
#pragma unroll
    for (int j = 0; j < 4; ++j)
#pragma unroll
      for (int r = 0; r < 4; ++r)
        R[w * 1088 + (quad * 4 + r) * 68 + j * 16 + l16] = acc[i][j][r];
    __syncthreads();
    const int d = t >> 2;            // 0..63
    const int ng = (t & 3) * 4;      // 0,4,8,12
    float4 o4;
    float* op = &o4.x;
#pragma unroll
    for (int nn = 0; nn < 4; ++nn) {
      int nl = ng + nn;
      float s = R[0 * 1088 + nl * 68 + d] + R[1 * 1088 + nl * 68 + d] +
                R[2 * 1088 + nl * 68 + d] + R[3 * 1088 + nl * 68 + d];
      op[nn] = s * rden[i * 16 + nl];
    }
    *(float4*)&y[((size_t)b * 512 + h * 64 + d) * N + n0 + i * 16 + ng] = o4;
  }
}

// ---------------------------------------------------------------------------
// Depthwise 3x3 conv (SAME) on v (fp32, natural layout) + BN, += into y.
// ---------------------------------------------------------------------------
__global__ __launch_bounds__(256) void pe_add_kernel(
    const float* __restrict__ vf, const float* __restrict__ pw,
    const float* __restrict__ gamma, const float* __restrict__ beta,
    const float* __restrict__ mean, const float* __restrict__ var,
    float* __restrict__ y) {
  const int idx = blockIdx.x * 256 + threadIdx.x;  // over 8*512*1600
  const int n = idx % 1600;
  const int bc = idx / 1600;
  const int c = bc % 512;
  const int b = bc / 512;
  const int hh = n / 40, ww = n % 40;
  const float* v = vf + (size_t)(b * 512 + c) * 1600;
  const float* wk = pw + c * 9;

  float s = 0.f;
#pragma unroll
  for (int dy = -1; dy <= 1; ++dy) {
#pragma unroll
    for (int dx = -1; dx <= 1; ++dx) {
      int yy = hh + dy, xx = ww + dx;
      if (yy >= 0 && yy < 40 && xx >= 0 && xx < 40)
        s += wk[(dy + 1) * 3 + (dx + 1)] * v[yy * 40 + xx];
    }
  }
  float inv = gamma[c] * rsqrtf(var[c] + EPS);
  y[idx] += s * inv + (beta[c] - mean[c] * inv);
}

// ---------------------------------------------------------------------------
extern "C" void kernel_launch(void* const* d_in, const int* in_sizes, int n_in,
                              void* d_out, int out_size, void* d_ws, size_t ws_size,
                              hipStream_t stream) {
  const float* x          = (const float*)d_in[0];
  const float* qkv_w      = (const float*)d_in[1];
  const float* qkv_gamma  = (const float*)d_in[2];
  const float* qkv_beta   = (const float*)d_in[3];
  const float* qkv_mean   = (const float*)d_in[4];
  const float* qkv_var    = (const float*)d_in[5];
  const float* pe_w       = (const float*)d_in[6];
  const float* pe_gamma   = (const float*)d_in[7];
  const float* pe_beta    = (const float*)d_in[8];
  const float* pe_mean    = (const float*)d_in[9];
  const float* pe_var     = (const float*)d_in[10];
  const float* proj_w     = (const float*)d_in[11];
  const float* proj_gamma = (const float*)d_in[12];
  const float* proj_beta  = (const float*)d_in[13];
  const float* proj_mean  = (const float*)d_in[14];
  const float* proj_var   = (const float*)d_in[15];
  float* out = (float*)d_out;

  // workspace layout (total 78,643,200 B, same footprint as round 1):
  //   vf  fp32 (B,512,1600)  26,214,400 B
  //   y   fp32 (B,512,1600)  26,214,400 B
  //   qT  bf16 (B,8,1600,32)  6,553,600 B
  //   kT  bf16 (B,8,1600,32)  6,553,600 B
  //   vb  bf16 (B,512,1600)  13,107,200 B
  float* vf   = (float*)d_ws;
  float* ws_y = vf + (size_t)6553600;
  short* qT   = (short*)(ws_y + (size_t)6553600);
  short* kT   = qT + (size_t)3276800;
  short* vb   = kT + (size_t)3276800;

  // 1) QKV conv1x1 + BN, split outputs (qT/kT bf16 transposed, v fp32+bf16)
  {
    dim3 grid(1600 / TILE, 1024 / TILE, 8), block(16, 16);
    qkv_gemm_kernel<<<grid, block, 0, stream>>>(
        x, qkv_w, qkv_gamma, qkv_beta, qkv_mean, qkv_var, qT, kT, vf, vb);
  }
  // 2) MFMA attention -> y
  {
    dim3 grid(1600 / 64, 64), block(256);
    attn_mfma_kernel<<<grid, block, 0, stream>>>(qT, kT, vb, ws_y);
  }
  // 3) y += BN(dwconv3x3(v, pe_w))
  {
    dim3 grid(8 * 512 * 1600 / 256), block(256);
    pe_add_kernel<<<grid, block, 0, stream>>>(
        vf, pe_w, pe_gamma, pe_beta, pe_mean, pe_var, ws_y);
  }
  // 4) out = BN(conv1x1(y, proj_w))
  {
    dim3 grid(1600 / TILE, 512 / TILE, 8), block(16, 16);
    gemm_bn_kernel<<<grid, block, 0, stream>>>(
        ws_y, proj_w, proj_gamma, proj_beta, proj_mean, proj_var, out, 512, 512, 1600);
  }
}

// Round 3
// 428.580 us; speedup vs baseline: 12.1737x; 1.3534x over previous
//
#include <hip/hip_runtime.h>
#include <hip/hip_bf16.h>

#define EPS 1e-5f
#define SCALE 0.17677669529663687f   // 32^-0.5

typedef __attribute__((ext_vector_type(8))) short bf16x8;
typedef __attribute__((ext_vector_type(4))) float f32x4;
typedef __attribute__((ext_vector_type(8))) unsigned short u16x8;

__device__ __forceinline__ unsigned short f2bf(float x) {
  union { float f; unsigned int u; } a; a.f = x;
  unsigned int r = a.u + 0x7FFFu + ((a.u >> 16) & 1u);
  return (unsigned short)(r >> 16);
}
__device__ __forceinline__ float bf2f(unsigned short u) {
  union { unsigned int u; float f; } a; a.u = ((unsigned int)u) << 16;
  return a.f;
}

// ---------------------------------------------------------------------------
// Cast qkv_w (1024x512) and proj_w (512x512) fp32 -> bf16, same layout.
// 196608 float4-threads total.
// ---------------------------------------------------------------------------
__global__ __launch_bounds__(256) void cast_w_kernel(
    const float* __restrict__ qw, const float* __restrict__ pw,
    short* __restrict__ wq, short* __restrict__ wp) {
  int idx = blockIdx.x * 256 + threadIdx.x;
  const float4* src;
  ushort4* dst;
  if (idx < 131072) {
    src = (const float4*)qw + idx;
    dst = (ushort4*)wq + idx;
  } else {
    src = (const float4*)pw + (idx - 131072);
    dst = (ushort4*)wp + (idx - 131072);
  }
  float4 v = *src;
  ushort4 u;
  u.x = f2bf(v.x); u.y = f2bf(v.y); u.z = f2bf(v.z); u.w = f2bf(v.w);
  *dst = u;
}

// ---------------------------------------------------------------------------
// Transpose-cast X (B,512,1600) fp32 -> XT (B,1600,512) bf16. 64x64 LDS tile.
// ---------------------------------------------------------------------------
__global__ __launch_bounds__(256) void transpose_cast_kernel(
    const float* __restrict__ X, short* __restrict__ XT) {
  __shared__ unsigned short T[64][72];  // [n_local][c_local], stride 72 -> 16B-aligned rows
  const int b = blockIdx.z, c0 = blockIdx.x * 64, n0 = blockIdx.y * 64;
  const int t = threadIdx.x, nl = t & 63, w = t >> 6;
#pragma unroll
  for (int ci = 0; ci < 16; ++ci) {
    int cl = ci * 4 + w;
    T[nl][cl] = f2bf(X[((size_t)(b * 512 + c0 + cl)) * 1600 + n0 + nl]);
  }
  __syncthreads();
  const int n2 = t >> 2, cg = (t & 3) * 16;
  unsigned short* o = (unsigned short*)XT + ((size_t)(b * 1600 + n0 + n2)) * 512 + c0 + cg;
  *(u16x8*)&o[0] = *(const u16x8*)&T[n2][cg];
  *(u16x8*)&o[8] = *(const u16x8*)&T[n2][cg + 8];
}

// ---------------------------------------------------------------------------
// QKV GEMM via MFMA. A = WQ (1024x512 bf16), B = XT (B,1600,512 bf16).
// Block: 128(o) x 64(n) tile = one head; 4 waves, wave w = o-rows [w*32,w*32+32).
// Epilogue: wave0 -> qT (SCALE folded), wave1 -> kT, waves2-3 -> vb.
// ---------------------------------------------------------------------------
__global__ __launch_bounds__(256) void qkv_mfma_kernel(
    const short* __restrict__ XT, const short* __restrict__ WQ,
    const float* __restrict__ gamma, const float* __restrict__ beta,
    const float* __restrict__ mean, const float* __restrict__ var,
    short* __restrict__ qT, short* __restrict__ kT, short* __restrict__ vb) {
  const int N = 1600;
  const int t = threadIdx.x, w = t >> 6, lane = t & 63;
  const int quad = lane >> 4, l16 = lane & 15;
  const int h = blockIdx.x;
  const int o0 = h * 128 + w * 32;
  const int n0 = blockIdx.y * 64;
  const int b = blockIdx.z;

  const short* Ab = WQ + (size_t)o0 * 512;
  const short* Bb = XT + ((size_t)b * N + n0) * 512;

  f32x4 acc[2][4];
#pragma unroll
  for (int mi = 0; mi < 2; ++mi)
#pragma unroll
    for (int nj = 0; nj < 4; ++nj) { acc[mi][nj][0]=0.f; acc[mi][nj][1]=0.f; acc[mi][nj][2]=0.f; acc[mi][nj][3]=0.f; }

  for (int c0 = 0; c0 < 512; c0 += 32) {
    bf16x8 af[2], bfg[4];
#pragma unroll
    for (int mi = 0; mi < 2; ++mi)
      af[mi] = *(const bf16x8*)&Ab[(size_t)(mi * 16 + l16) * 512 + c0 + quad * 8];
#pragma unroll
    for (int nj = 0; nj < 4; ++nj)
      bfg[nj] = *(const bf16x8*)&Bb[(size_t)(nj * 16 + l16) * 512 + c0 + quad * 8];
#pragma unroll
    for (int mi = 0; mi < 2; ++mi)
#pragma unroll
      for (int nj = 0; nj < 4; ++nj)
        acc[mi][nj] = __builtin_amdgcn_mfma_f32_16x16x32_bf16(af[mi], bfg[nj], acc[mi][nj], 0, 0, 0);
  }

#pragma unroll
  for (int mi = 0; mi < 2; ++mi) {
    const int ob = o0 + mi * 16 + quad * 4;
    float inv[4], add[4];
#pragma unroll
    for (int r = 0; r < 4; ++r) {
      inv[r] = gamma[ob + r] * rsqrtf(var[ob + r] + EPS);
      add[r] = beta[ob + r] - mean[ob + r] * inv[r];
    }
    if (w == 0) {        // q rows: kk = mi*16+quad*4+r, pre-scale
      const int kk = mi * 16 + quad * 4;
#pragma unroll
      for (int nj = 0; nj < 4; ++nj) {
        int n = n0 + nj * 16 + l16;
        ushort4 u;
        u.x = f2bf((acc[mi][nj][0] * inv[0] + add[0]) * SCALE);
        u.y = f2bf((acc[mi][nj][1] * inv[1] + add[1]) * SCALE);
        u.z = f2bf((acc[mi][nj][2] * inv[2] + add[2]) * SCALE);
        u.w = f2bf((acc[mi][nj][3] * inv[3] + add[3]) * SCALE);
        *(ushort4*)&qT[(((size_t)(b * 8 + h) * N + n)) * 32 + kk] = u;
      }
    } else if (w == 1) { // k rows
      const int kk = mi * 16 + quad * 4;
#pragma unroll
      for (int nj = 0; nj < 4; ++nj) {
        int n = n0 + nj * 16 + l16;
        ushort4 u;
        u.x = f2bf(acc[mi][nj][0] * inv[0] + add[0]);
        u.y = f2bf(acc[mi][nj][1] * inv[1] + add[1]);
        u.z = f2bf(acc[mi][nj][2] * inv[2] + add[2]);
        u.w = f2bf(acc[mi][nj][3] * inv[3] + add[3]);
        *(ushort4*)&kT[(((size_t)(b * 8 + h) * N + n)) * 32 + kk] = u;
      }
    } else {             // v rows -> vb (B,512,N) bf16
      const int ch = h * 64 + (w - 2) * 32 + mi * 16 + quad * 4;
#pragma unroll
      for (int nj = 0; nj < 4; ++nj) {
        int n = n0 + nj * 16 + l16;
#pragma unroll
        for (int r = 0; r < 4; ++r)
          ((unsigned short*)vb)[((size_t)(b * 512 + ch + r)) * N + n] =
              f2bf(acc[mi][nj][r] * inv[r] + add[r]);
      }
    }
  }
}

// ---------------------------------------------------------------------------
// MFMA flash-style attention (unchanged from round 2).
// ---------------------------------------------------------------------------
__global__ __launch_bounds__(256) void attn_mfma_kernel(
    const short* __restrict__ qT, const short* __restrict__ kT,
    const short* __restrict__ vb, float* __restrict__ y) {
  const int N = 1600;
  const int PS = 72;
  __shared__ __align__(16) unsigned short Plds[4][64 * PS];
  __shared__ float den_lds[4][64];
  __shared__ float rden[64];

  const int t = threadIdx.x;
  const int w = t >> 6, lane = t & 63, quad = lane >> 4, l16 = lane & 15;
  const int bh = blockIdx.y, b = bh >> 3, h = bh & 7;
  const int n0 = blockIdx.x * 64;

  const short* qTb = qT + (size_t)(b * 8 + h) * N * 32;
  const short* kTb = kT + (size_t)(b * 8 + h) * N * 32;
  const short* vbb = vb + ((size_t)b * 512 + h * 64) * N;

  bf16x8 qf[4];
#pragma unroll
  for (int i = 0; i < 4; ++i)
    qf[i] = *(const bf16x8*)(qTb + (size_t)(n0 + i * 16 + l16) * 32 + quad * 8);

  f32x4 acc[4][4];
#pragma unroll
  for (int i = 0; i < 4; ++i)
#pragma unroll
    for (int j = 0; j < 4; ++j) { acc[i][j][0] = 0.f; acc[i][j][1] = 0.f; acc[i][j][2] = 0.f; acc[i][j][3] = 0.f; }
  float den[4][4] = {};

  unsigned short* Pw = &Plds[w][0];
  const f32x4 zero4 = {0.f, 0.f, 0.f, 0.f};

  for (int mt = w; mt < 25; mt += 4) {
    const int m0 = mt * 64;
    bf16x8 kf[4];
#pragma unroll
    for (int j = 0; j < 4; ++j)
      kf[j] = *(const bf16x8*)(kTb + (size_t)(m0 + j * 16 + l16) * 32 + quad * 8);

#pragma unroll
    for (int i = 0; i < 4; ++i) {
#pragma unroll
      for (int j = 0; j < 4; ++j) {
        f32x4 s = __builtin_amdgcn_mfma_f32_16x16x32_bf16(qf[i], kf[j], zero4, 0, 0, 0);
#pragma unroll
        for (int r = 0; r < 4; ++r) {
          float p = __expf(s[r]);
          den[i][r] += p;
          Pw[(i * 16 + quad * 4 + r) * PS + j * 16 + l16] = f2bf(p);
        }
      }
    }

    bf16x8 pf[4][2];
#pragma unroll
    for (int i = 0; i < 4; ++i)
#pragma unroll
      for (int c = 0; c < 2; ++c)
        pf[i][c] = *(const bf16x8*)(Pw + (i * 16 + l16) * PS + c * 32 + quad * 8);

#pragma unroll
    for (int c = 0; c < 2; ++c) {
#pragma unroll
      for (int j = 0; j < 4; ++j) {
        bf16x8 vfr = *(const bf16x8*)(vbb + (size_t)(j * 16 + l16) * N + m0 + c * 32 + quad * 8);
#pragma unroll
        for (int i = 0; i < 4; ++i)
          acc[i][j] = __builtin_amdgcn_mfma_f32_16x16x32_bf16(pf[i][c], vfr, acc[i][j], 0, 0, 0);
      }
    }
  }

#pragma unroll
  for (int mask = 1; mask <= 8; mask <<= 1)
#pragma unroll
    for (int i = 0; i < 4; ++i)
#pragma unroll
      for (int r = 0; r < 4; ++r)
        den[i][r] += __shfl_xor(den[i][r], mask, 64);
  if (l16 == 0) {
#pragma unroll
    for (int i = 0; i < 4; ++i)
#pragma unroll
      for (int r = 0; r < 4; ++r)
        den_lds[w][i * 16 + quad * 4 + r] = den[i][r];
  }
  __syncthreads();
  if (t < 64)
    rden[t] = 1.f / (den_lds[0][t] + den_lds[1][t] + den_lds[2][t] + den_lds[3][t]);

  float* R = (float*)&Plds[0][0];
#pragma unroll 1
  for (int i = 0; i < 4; ++i) {
    __syncthreads();
#pragma unroll
    for (int j = 0; j < 4; ++j)
#pragma unroll
      for (int r = 0; r < 4; ++r)
        R[w * 1088 + (quad * 4 + r) * 68 + j * 16 + l16] = acc[i][j][r];
    __syncthreads();
    const int d = t >> 2;
    const int ng = (t & 3) * 4;
    float4 o4;
    float* op = &o4.x;
#pragma unroll
    for (int nn = 0; nn < 4; ++nn) {
      int nl = ng + nn;
      float s = R[0 * 1088 + nl * 68 + d] + R[1 * 1088 + nl * 68 + d] +
                R[2 * 1088 + nl * 68 + d] + R[3 * 1088 + nl * 68 + d];
      op[nn] = s * rden[i * 16 + nl];
    }
    *(float4*)&y[((size_t)b * 512 + h * 64 + d) * N + n0 + i * 16 + ng] = o4;
  }
}

// ---------------------------------------------------------------------------
// PE: yT = bf16( y + BN(dwconv3x3(v)) ), transposed to (B,1600,512).
// v read from vb (bf16). 64c x 64n LDS tile per block.
// ---------------------------------------------------------------------------
__global__ __launch_bounds__(256) void pe_transpose_kernel(
    const float* __restrict__ Y, const short* __restrict__ VB,
    const float* __restrict__ pw,
    const float* __restrict__ gamma, const float* __restrict__ beta,
    const float* __restrict__ mean, const float* __restrict__ var,
    short* __restrict__ YT) {
  __shared__ unsigned short T[64][72];
  const int b = blockIdx.z, c0 = blockIdx.x * 64, n0 = blockIdx.y * 64;
  const int t = threadIdx.x, nl = t & 63, w = t >> 6;
  const int n = n0 + nl;
  const int hh = n / 40, ww = n % 40;

#pragma unroll 4
  for (int ci = 0; ci < 16; ++ci) {
    int cl = ci * 4 + w, c = c0 + cl;
    const unsigned short* v = (const unsigned short*)VB + (size_t)(b * 512 + c) * 1600;
    const float* wk = pw + c * 9;
    float s = 0.f;
#pragma unroll
    for (int dy = -1; dy <= 1; ++dy)
#pragma unroll
      for (int dx = -1; dx <= 1; ++dx) {
        int yy = hh + dy, xx = ww + dx;
        if (yy >= 0 && yy < 40 && xx >= 0 && xx < 40)
          s += wk[(dy + 1) * 3 + (dx + 1)] * bf2f(v[yy * 40 + xx]);
      }
    float inv = gamma[c] * rsqrtf(var[c] + EPS);
    float val = Y[(size_t)(b * 512 + c) * 1600 + n] + s * inv + (beta[c] - mean[c] * inv);
    T[nl][cl] = f2bf(val);
  }
  __syncthreads();
  const int n2 = t >> 2, cg = (t & 3) * 16;
  unsigned short* o = (unsigned short*)YT + ((size_t)(b * 1600 + n0 + n2)) * 512 + c0 + cg;
  *(u16x8*)&o[0] = *(const u16x8*)&T[n2][cg];
  *(u16x8*)&o[8] = *(const u16x8*)&T[n2][cg + 8];
}

// ---------------------------------------------------------------------------
// Proj GEMM via MFMA + BN -> out fp32 (B,512,1600).
// ---------------------------------------------------------------------------
__global__ __launch_bounds__(256) void proj_mfma_kernel(
    const short* __restrict__ YT, const short* __restrict__ WP,
    const float* __restrict__ gamma, const float* __restrict__ beta,
    const float* __restrict__ mean, const float* __restrict__ var,
    float* __restrict__ OUT) {
  const int N = 1600;
  const int t = threadIdx.x, w = t >> 6, lane = t & 63;
  const int quad = lane >> 4, l16 = lane & 15;
  const int o0 = blockIdx.x * 128 + w * 32;
  const int n0 = blockIdx.y * 64;
  const int b = blockIdx.z;

  const short* Ab = WP + (size_t)o0 * 512;
  const short* Bb = YT + ((size_t)b * N + n0) * 512;

  f32x4 acc[2][4];
#pragma unroll
  for (int mi = 0; mi < 2; ++mi)
#pragma unroll
    for (int nj = 0; nj < 4; ++nj) { acc[mi][nj][0]=0.f; acc[mi][nj][1]=0.f; acc[mi][nj][2]=0.f; acc[mi][nj][3]=0.f; }

  for (int c0 = 0; c0 < 512; c0 += 32) {
    bf16x8 af[2], bfg[4];
#pragma unroll
    for (int mi = 0; mi < 2; ++mi)
      af[mi] = *(const bf16x8*)&Ab[(size_t)(mi * 16 + l16) * 512 + c0 + quad * 8];
#pragma unroll
    for (int nj = 0; nj < 4; ++nj)
      bfg[nj] = *(const bf16x8*)&Bb[(size_t)(nj * 16 + l16) * 512 + c0 + quad * 8];
#pragma unroll
    for (int mi = 0; mi < 2; ++mi)
#pragma unroll
      for (int nj = 0; nj < 4; ++nj)
        acc[mi][nj] = __builtin_amdgcn_mfma_f32_16x16x32_bf16(af[mi], bfg[nj], acc[mi][nj], 0, 0, 0);
  }

#pragma unroll
  for (int mi = 0; mi < 2; ++mi) {
    const int ob = o0 + mi * 16 + quad * 4;
    float inv[4], add[4];
#pragma unroll
    for (int r = 0; r < 4; ++r) {
      inv[r] = gamma[ob + r] * rsqrtf(var[ob + r] + EPS);
      add[r] = beta[ob + r] - mean[ob + r] * inv[r];
    }
#pragma unroll
    for (int nj = 0; nj < 4; ++nj) {
      int n = n0 + nj * 16 + l16;
#pragma unroll
      for (int r = 0; r < 4; ++r)
        OUT[((size_t)(b * 512 + ob + r)) * N + n] = acc[mi][nj][r] * inv[r] + add[r];
    }
  }
}

// ---------------------------------------------------------------------------
extern "C" void kernel_launch(void* const* d_in, const int* in_sizes, int n_in,
                              void* d_out, int out_size, void* d_ws, size_t ws_size,
                              hipStream_t stream) {
  const float* x          = (const float*)d_in[0];
  const float* qkv_w      = (const float*)d_in[1];
  const float* qkv_gamma  = (const float*)d_in[2];
  const float* qkv_beta   = (const float*)d_in[3];
  const float* qkv_mean   = (const float*)d_in[4];
  const float* qkv_var    = (const float*)d_in[5];
  const float* pe_w       = (const float*)d_in[6];
  const float* pe_gamma   = (const float*)d_in[7];
  const float* pe_beta    = (const float*)d_in[8];
  const float* pe_mean    = (const float*)d_in[9];
  const float* pe_var     = (const float*)d_in[10];
  const float* proj_w     = (const float*)d_in[11];
  const float* proj_gamma = (const float*)d_in[12];
  const float* proj_beta  = (const float*)d_in[13];
  const float* proj_mean  = (const float*)d_in[14];
  const float* proj_var   = (const float*)d_in[15];
  float* out = (float*)d_out;

  // workspace (64 MB total):
  //   y    fp32 (B,512,1600)    26,214,400 B
  //   qT   bf16 (B,8,1600,32)    6,553,600 B
  //   kT   bf16 (B,8,1600,32)    6,553,600 B
  //   vb   bf16 (B,512,1600)    13,107,200 B
  //   xT   bf16 (B,1600,512)    13,107,200 B   (reused as yT after qkv GEMM)
  //   wq   bf16 (1024,512)       1,048,576 B
  //   wp   bf16 (512,512)          524,288 B
  float* ws_y = (float*)d_ws;
  short* qT   = (short*)(ws_y + (size_t)6553600);
  short* kT   = qT + (size_t)3276800;
  short* vb   = kT + (size_t)3276800;
  short* xT   = vb + (size_t)6553600;   // aliased as yT later
  short* wq   = xT + (size_t)6553600;
  short* wp   = wq + (size_t)524288;
  short* yT   = xT;

  // 1) weights -> bf16
  cast_w_kernel<<<768, 256, 0, stream>>>(qkv_w, proj_w, wq, wp);
  // 2) x -> xT (B,1600,512) bf16
  {
    dim3 grid(8, 25, 8), block(256);
    transpose_cast_kernel<<<grid, block, 0, stream>>>(x, xT);
  }
  // 3) QKV MFMA GEMM + BN -> qT, kT, vb
  {
    dim3 grid(8, 25, 8), block(256);
    qkv_mfma_kernel<<<grid, block, 0, stream>>>(
        xT, wq, qkv_gamma, qkv_beta, qkv_mean, qkv_var, qT, kT, vb);
  }
  // 4) attention -> y (fp32, c-major)
  {
    dim3 grid(25, 64), block(256);
    attn_mfma_kernel<<<grid, block, 0, stream>>>(qT, kT, vb, ws_y);
  }
  // 5) yT = bf16(y + BN(dwconv3x3(v)))   (transposed for proj)
  {
    dim3 grid(8, 25, 8), block(256);
    pe_transpose_kernel<<<grid, block, 0, stream>>>(
        ws_y, vb, pe_w, pe_gamma, pe_beta, pe_mean, pe_var, yT);
  }
  // 6) out = BN(conv1x1(yT, wp))
  {
    dim3 grid(4, 25, 8), block(256);
    proj_mfma_kernel<<<grid, block, 0, stream>>>(
        yT, wp, proj_gamma, proj_beta, proj_mean, proj_var, out);
  }
}

// Round 4
// 366.992 us; speedup vs baseline: 14.2167x; 1.1678x over previous
//
#include <hip/hip_runtime.h>
#include <hip/hip_bf16.h>

#define EPS 1e-5f
#define SCALE 0.17677669529663687f   // 32^-0.5

typedef __attribute__((ext_vector_type(8))) short bf16x8;
typedef __attribute__((ext_vector_type(4))) float f32x4;
typedef __attribute__((ext_vector_type(8))) unsigned short u16x8;

__device__ __forceinline__ unsigned short f2bf(float x) {
  union { float f; unsigned int u; } a; a.f = x;
  unsigned int r = a.u + 0x7FFFu + ((a.u >> 16) & 1u);
  return (unsigned short)(r >> 16);
}
__device__ __forceinline__ float bf2f(unsigned short u) {
  union { unsigned int u; float f; } a; a.u = ((unsigned int)u) << 16;
  return a.f;
}

// ---------------------------------------------------------------------------
// Cast qkv_w (1024x512) and proj_w (512x512) fp32 -> bf16, same layout.
// ---------------------------------------------------------------------------
__global__ __launch_bounds__(256) void cast_w_kernel(
    const float* __restrict__ qw, const float* __restrict__ pw,
    short* __restrict__ wq, short* __restrict__ wp) {
  int idx = blockIdx.x * 256 + threadIdx.x;
  const float4* src;
  ushort4* dst;
  if (idx < 131072) {
    src = (const float4*)qw + idx;
    dst = (ushort4*)wq + idx;
  } else {
    src = (const float4*)pw + (idx - 131072);
    dst = (ushort4*)wp + (idx - 131072);
  }
  float4 v = *src;
  ushort4 u;
  u.x = f2bf(v.x); u.y = f2bf(v.y); u.z = f2bf(v.z); u.w = f2bf(v.w);
  *dst = u;
}

// ---------------------------------------------------------------------------
// Transpose-cast X (B,512,1600) fp32 -> XT (B,1600,512) bf16. 64x64 LDS tile.
// ---------------------------------------------------------------------------
__global__ __launch_bounds__(256) void transpose_cast_kernel(
    const float* __restrict__ X, short* __restrict__ XT) {
  __shared__ unsigned short T[64][72];
  const int b = blockIdx.z, c0 = blockIdx.x * 64, n0 = blockIdx.y * 64;
  const int t = threadIdx.x, nl = t & 63, w = t >> 6;
#pragma unroll
  for (int ci = 0; ci < 16; ++ci) {
    int cl = ci * 4 + w;
    T[nl][cl] = f2bf(X[((size_t)(b * 512 + c0 + cl)) * 1600 + n0 + nl]);
  }
  __syncthreads();
  const int n2 = t >> 2, cg = (t & 3) * 16;
  unsigned short* o = (unsigned short*)XT + ((size_t)(b * 1600 + n0 + n2)) * 512 + c0 + cg;
  *(u16x8*)&o[0] = *(const u16x8*)&T[n2][cg];
  *(u16x8*)&o[8] = *(const u16x8*)&T[n2][cg + 8];
}

// ---------------------------------------------------------------------------
// QKV GEMM via MFMA (unchanged from round 3).
// ---------------------------------------------------------------------------
__global__ __launch_bounds__(256) void qkv_mfma_kernel(
    const short* __restrict__ XT, const short* __restrict__ WQ,
    const float* __restrict__ gamma, const float* __restrict__ beta,
    const float* __restrict__ mean, const float* __restrict__ var,
    short* __restrict__ qT, short* __restrict__ kT, short* __restrict__ vb) {
  const int N = 1600;
  const int t = threadIdx.x, w = t >> 6, lane = t & 63;
  const int quad = lane >> 4, l16 = lane & 15;
  const int h = blockIdx.x;
  const int o0 = h * 128 + w * 32;
  const int n0 = blockIdx.y * 64;
  const int b = blockIdx.z;

  const short* Ab = WQ + (size_t)o0 * 512;
  const short* Bb = XT + ((size_t)b * N + n0) * 512;

  f32x4 acc[2][4];
#pragma unroll
  for (int mi = 0; mi < 2; ++mi)
#pragma unroll
    for (int nj = 0; nj < 4; ++nj) { acc[mi][nj][0]=0.f; acc[mi][nj][1]=0.f; acc[mi][nj][2]=0.f; acc[mi][nj][3]=0.f; }

  for (int c0 = 0; c0 < 512; c0 += 32) {
    bf16x8 af[2], bfg[4];
#pragma unroll
    for (int mi = 0; mi < 2; ++mi)
      af[mi] = *(const bf16x8*)&Ab[(size_t)(mi * 16 + l16) * 512 + c0 + quad * 8];
#pragma unroll
    for (int nj = 0; nj < 4; ++nj)
      bfg[nj] = *(const bf16x8*)&Bb[(size_t)(nj * 16 + l16) * 512 + c0 + quad * 8];
#pragma unroll
    for (int mi = 0; mi < 2; ++mi)
#pragma unroll
      for (int nj = 0; nj < 4; ++nj)
        acc[mi][nj] = __builtin_amdgcn_mfma_f32_16x16x32_bf16(af[mi], bfg[nj], acc[mi][nj], 0, 0, 0);
  }

#pragma unroll
  for (int mi = 0; mi < 2; ++mi) {
    const int ob = o0 + mi * 16 + quad * 4;
    float inv[4], add[4];
#pragma unroll
    for (int r = 0; r < 4; ++r) {
      inv[r] = gamma[ob + r] * rsqrtf(var[ob + r] + EPS);
      add[r] = beta[ob + r] - mean[ob + r] * inv[r];
    }
    if (w == 0) {
      const int kk = mi * 16 + quad * 4;
#pragma unroll
      for (int nj = 0; nj < 4; ++nj) {
        int n = n0 + nj * 16 + l16;
        ushort4 u;
        u.x = f2bf((acc[mi][nj][0] * inv[0] + add[0]) * SCALE);
        u.y = f2bf((acc[mi][nj][1] * inv[1] + add[1]) * SCALE);
        u.z = f2bf((acc[mi][nj][2] * inv[2] + add[2]) * SCALE);
        u.w = f2bf((acc[mi][nj][3] * inv[3] + add[3]) * SCALE);
        *(ushort4*)&qT[(((size_t)(b * 8 + h) * N + n)) * 32 + kk] = u;
      }
    } else if (w == 1) {
      const int kk = mi * 16 + quad * 4;
#pragma unroll
      for (int nj = 0; nj < 4; ++nj) {
        int n = n0 + nj * 16 + l16;
        ushort4 u;
        u.x = f2bf(acc[mi][nj][0] * inv[0] + add[0]);
        u.y = f2bf(acc[mi][nj][1] * inv[1] + add[1]);
        u.z = f2bf(acc[mi][nj][2] * inv[2] + add[2]);
        u.w = f2bf(acc[mi][nj][3] * inv[3] + add[3]);
        *(ushort4*)&kT[(((size_t)(b * 8 + h) * N + n)) * 32 + kk] = u;
      }
    } else {
      const int ch = h * 64 + (w - 2) * 32 + mi * 16 + quad * 4;
#pragma unroll
      for (int nj = 0; nj < 4; ++nj) {
        int n = n0 + nj * 16 + l16;
#pragma unroll
        for (int r = 0; r < 4; ++r)
          ((unsigned short*)vb)[((size_t)(b * 512 + ch + r)) * N + n] =
              f2bf(acc[mi][nj][r] * inv[r] + add[r]);
      }
    }
  }
}

// ---------------------------------------------------------------------------
// MFMA flash attention, cooperative per-m-tile version (low register).
// Block = 4 waves, 64 queries. Per m-tile of 64 keys:
//   phase 1: wave w computes S slice (64n x 16m, cols w*16..) -> exp -> P LDS
//   phase 2: wave w computes PV for its d-slice [w*16, w*16+16)
// Per-wave state: acc[4] (16 VGPR) + qf 16 + den 16 -> no spill.
// ---------------------------------------------------------------------------
__global__ __launch_bounds__(256) void attn_mfma_kernel(
    const short* __restrict__ qT, const short* __restrict__ kT,
    const short* __restrict__ vb, float* __restrict__ y) {
  const int N = 1600;
  const int PS = 72;  // P row stride (shorts); 16B-aligned b128 rows
  __shared__ __align__(16) unsigned short Plds[64 * PS];  // 9216 B
  __shared__ float den_lds[4][64];
  __shared__ float rden[64];

  const int t = threadIdx.x;
  const int w = t >> 6, lane = t & 63, quad = lane >> 4, l16 = lane & 15;
  const int bh = blockIdx.y, b = bh >> 3, h = bh & 7;
  const int n0 = blockIdx.x * 64;

  const short* qTb = qT + (size_t)(b * 8 + h) * N * 32;
  const short* kTb = kT + (size_t)(b * 8 + h) * N * 32;
  const short* vbb = vb + ((size_t)b * 512 + h * 64) * N;

  // q A-fragments (same for all waves), resident across the m-loop
  bf16x8 qf[4];
#pragma unroll
  for (int i = 0; i < 4; ++i)
    qf[i] = *(const bf16x8*)(qTb + (size_t)(n0 + i * 16 + l16) * 32 + quad * 8);

  f32x4 acc[4];
#pragma unroll
  for (int i = 0; i < 4; ++i) { acc[i][0]=0.f; acc[i][1]=0.f; acc[i][2]=0.f; acc[i][3]=0.f; }
  float den[4][4] = {};
  const f32x4 zero4 = {0.f, 0.f, 0.f, 0.f};

  for (int mt = 0; mt < 25; ++mt) {
    const int m0 = mt * 64;
    // phase 1: S slice for cols m0 + w*16 .. +16
    bf16x8 kf = *(const bf16x8*)(kTb + (size_t)(m0 + w * 16 + l16) * 32 + quad * 8);
#pragma unroll
    for (int i = 0; i < 4; ++i) {
      f32x4 s = __builtin_amdgcn_mfma_f32_16x16x32_bf16(qf[i], kf, zero4, 0, 0, 0);
#pragma unroll
      for (int r = 0; r < 4; ++r) {
        float p = __expf(s[r]);
        den[i][r] += p;                 // this lane covers m-col w*16+l16
        Plds[(i * 16 + quad * 4 + r) * PS + w * 16 + l16] = f2bf(p);
      }
    }
    __syncthreads();
    // phase 2: PV for d-slice w*16..w*16+16
#pragma unroll
    for (int c = 0; c < 2; ++c) {
      bf16x8 vfr = *(const bf16x8*)(vbb + (size_t)(w * 16 + l16) * N + m0 + c * 32 + quad * 8);
#pragma unroll
      for (int i = 0; i < 4; ++i) {
        bf16x8 pf = *(const bf16x8*)(Plds + (size_t)(i * 16 + l16) * PS + c * 32 + quad * 8);
        acc[i] = __builtin_amdgcn_mfma_f32_16x16x32_bf16(pf, vfr, acc[i], 0, 0, 0);
      }
    }
    __syncthreads();
  }

  // den: sum over the 16 lanes (m-cols), then over the 4 waves (m-slices)
#pragma unroll
  for (int mask = 1; mask <= 8; mask <<= 1)
#pragma unroll
    for (int i = 0; i < 4; ++i)
#pragma unroll
      for (int r = 0; r < 4; ++r)
        den[i][r] += __shfl_xor(den[i][r], mask, 64);
  if (l16 == 0) {
#pragma unroll
    for (int i = 0; i < 4; ++i)
#pragma unroll
      for (int r = 0; r < 4; ++r)
        den_lds[w][i * 16 + quad * 4 + r] = den[i][r];
  }
  __syncthreads();
  if (t < 64)
    rden[t] = 1.f / (den_lds[0][t] + den_lds[1][t] + den_lds[2][t] + den_lds[3][t]);
  __syncthreads();

  // write: lane owns d-row h*64 + w*16 + l16; acc[i] = 4 consecutive n
  float* yr = y + ((size_t)b * 512 + h * 64 + w * 16 + l16) * N + n0;
#pragma unroll
  for (int i = 0; i < 4; ++i) {
    const int nb = i * 16 + quad * 4;
    float4 o4;
    o4.x = acc[i][0] * rden[nb + 0];
    o4.y = acc[i][1] * rden[nb + 1];
    o4.z = acc[i][2] * rden[nb + 2];
    o4.w = acc[i][3] * rden[nb + 3];
    *(float4*)&yr[nb] = o4;
  }
}

// ---------------------------------------------------------------------------
// PE: yT = bf16( y + BN(dwconv3x3(v)) ), transposed to (B,1600,512).
// ---------------------------------------------------------------------------
__global__ __launch_bounds__(256) void pe_transpose_kernel(
    const float* __restrict__ Y, const short* __restrict__ VB,
    const float* __restrict__ pw,
    const float* __restrict__ gamma, const float* __restrict__ beta,
    const float* __restrict__ mean, const float* __restrict__ var,
    short* __restrict__ YT) {
  __shared__ unsigned short T[64][72];
  const int b = blockIdx.z, c0 = blockIdx.x * 64, n0 = blockIdx.y * 64;
  const int t = threadIdx.x, nl = t & 63, w = t >> 6;
  const int n = n0 + nl;
  const int hh = n / 40, ww = n % 40;

#pragma unroll 4
  for (int ci = 0; ci < 16; ++ci) {
    int cl = ci * 4 + w, c = c0 + cl;
    const unsigned short* v = (const unsigned short*)VB + (size_t)(b * 512 + c) * 1600;
    const float* wk = pw + c * 9;
    float s = 0.f;
#pragma unroll
    for (int dy = -1; dy <= 1; ++dy)
#pragma unroll
      for (int dx = -1; dx <= 1; ++dx) {
        int yy = hh + dy, xx = ww + dx;
        if (yy >= 0 && yy < 40 && xx >= 0 && xx < 40)
          s += wk[(dy + 1) * 3 + (dx + 1)] * bf2f(v[yy * 40 + xx]);
      }
    float inv = gamma[c] * rsqrtf(var[c] + EPS);
    float val = Y[(size_t)(b * 512 + c) * 1600 + n] + s * inv + (beta[c] - mean[c] * inv);
    T[nl][cl] = f2bf(val);
  }
  __syncthreads();
  const int n2 = t >> 2, cg = (t & 3) * 16;
  unsigned short* o = (unsigned short*)YT + ((size_t)(b * 1600 + n0 + n2)) * 512 + c0 + cg;
  *(u16x8*)&o[0] = *(const u16x8*)&T[n2][cg];
  *(u16x8*)&o[8] = *(const u16x8*)&T[n2][cg + 8];
}

// ---------------------------------------------------------------------------
// Proj GEMM via MFMA + BN -> out fp32 (B,512,1600).
// ---------------------------------------------------------------------------
__global__ __launch_bounds__(256) void proj_mfma_kernel(
    const short* __restrict__ YT, const short* __restrict__ WP,
    const float* __restrict__ gamma, const float* __restrict__ beta,
    const float* __restrict__ mean, const float* __restrict__ var,
    float* __restrict__ OUT) {
  const int N = 1600;
  const int t = threadIdx.x, w = t >> 6, lane = t & 63;
  const int quad = lane >> 4, l16 = lane & 15;
  const int o0 = blockIdx.x * 128 + w * 32;
  const int n0 = blockIdx.y * 64;
  const int b = blockIdx.z;

  const short* Ab = WP + (size_t)o0 * 512;
  const short* Bb = YT + ((size_t)b * N + n0) * 512;

  f32x4 acc[2][4];
#pragma unroll
  for (int mi = 0; mi < 2; ++mi)
#pragma unroll
    for (int nj = 0; nj < 4; ++nj) { acc[mi][nj][0]=0.f; acc[mi][nj][1]=0.f; acc[mi][nj][2]=0.f; acc[mi][nj][3]=0.f; }

  for (int c0 = 0; c0 < 512; c0 += 32) {
    bf16x8 af[2], bfg[4];
#pragma unroll
    for (int mi = 0; mi < 2; ++mi)
      af[mi] = *(const bf16x8*)&Ab[(size_t)(mi * 16 + l16) * 512 + c0 + quad * 8];
#pragma unroll
    for (int nj = 0; nj < 4; ++nj)
      bfg[nj] = *(const bf16x8*)&Bb[(size_t)(nj * 16 + l16) * 512 + c0 + quad * 8];
#pragma unroll
    for (int mi = 0; mi < 2; ++mi)
#pragma unroll
      for (int nj = 0; nj < 4; ++nj)
        acc[mi][nj] = __builtin_amdgcn_mfma_f32_16x16x32_bf16(af[mi], bfg[nj], acc[mi][nj], 0, 0, 0);
  }

#pragma unroll
  for (int mi = 0; mi < 2; ++mi) {
    const int ob = o0 + mi * 16 + quad * 4;
    float inv[4], add[4];
#pragma unroll
    for (int r = 0; r < 4; ++r) {
      inv[r] = gamma[ob + r] * rsqrtf(var[ob + r] + EPS);
      add[r] = beta[ob + r] - mean[ob + r] * inv[r];
    }
#pragma unroll
    for (int nj = 0; nj < 4; ++nj) {
      int n = n0 + nj * 16 + l16;
#pragma unroll
      for (int r = 0; r < 4; ++r)
        OUT[((size_t)(b * 512 + ob + r)) * N + n] = acc[mi][nj][r] * inv[r] + add[r];
    }
  }
}

// ---------------------------------------------------------------------------
extern "C" void kernel_launch(void* const* d_in, const int* in_sizes, int n_in,
                              void* d_out, int out_size, void* d_ws, size_t ws_size,
                              hipStream_t stream) {
  const float* x          = (const float*)d_in[0];
  const float* qkv_w      = (const float*)d_in[1];
  const float* qkv_gamma  = (const float*)d_in[2];
  const float* qkv_beta   = (const float*)d_in[3];
  const float* qkv_mean   = (const float*)d_in[4];
  const float* qkv_var    = (const float*)d_in[5];
  const float* pe_w       = (const float*)d_in[6];
  const float* pe_gamma   = (const float*)d_in[7];
  const float* pe_beta    = (const float*)d_in[8];
  const float* pe_mean    = (const float*)d_in[9];
  const float* pe_var     = (const float*)d_in[10];
  const float* proj_w     = (const float*)d_in[11];
  const float* proj_gamma = (const float*)d_in[12];
  const float* proj_beta  = (const float*)d_in[13];
  const float* proj_mean  = (const float*)d_in[14];
  const float* proj_var   = (const float*)d_in[15];
  float* out = (float*)d_out;

  // workspace layout (64 MB total)
  float* ws_y = (float*)d_ws;
  short* qT   = (short*)(ws_y + (size_t)6553600);
  short* kT   = qT + (size_t)3276800;
  short* vb   = kT + (size_t)3276800;
  short* xT   = vb + (size_t)6553600;   // aliased as yT later
  short* wq   = xT + (size_t)6553600;
  short* wp   = wq + (size_t)524288;
  short* yT   = xT;

  cast_w_kernel<<<768, 256, 0, stream>>>(qkv_w, proj_w, wq, wp);
  {
    dim3 grid(8, 25, 8), block(256);
    transpose_cast_kernel<<<grid, block, 0, stream>>>(x, xT);
  }
  {
    dim3 grid(8, 25, 8), block(256);
    qkv_mfma_kernel<<<grid, block, 0, stream>>>(
        xT, wq, qkv_gamma, qkv_beta, qkv_mean, qkv_var, qT, kT, vb);
  }
  {
    dim3 grid(25, 64), block(256);
    attn_mfma_kernel<<<grid, block, 0, stream>>>(qT, kT, vb, ws_y);
  }
  {
    dim3 grid(8, 25, 8), block(256);
    pe_transpose_kernel<<<grid, block, 0, stream>>>(
        ws_y, vb, pe_w, pe_gamma, pe_beta, pe_mean, pe_var, yT);
  }
  {
    dim3 grid(4, 25, 8), block(256);
    proj_mfma_kernel<<<grid, block, 0, stream>>>(
        yT, wp, proj_gamma, proj_beta, proj_mean, proj_var, out);
  }
}